// Round 12
// baseline (781.749 us; speedup 1.0000x reference)
//
#include <hip/hip_runtime.h>
#include <hip/hip_bf16.h>
#include <math.h>

#define B_ 4
#define N_ 256
#define L_ 4
#define H_ 256
#define D_ 128
#define DEG_ 16
#define T_ 64

// ws layout (float units)
#define OFF_H     0          // 262144 : h after fc+LN+tanh (f32) [B*N,256]
#define OFF_FCWT  262144     // 66048  : fc_w transposed [258][256]
#define OFF_BIAS  328192     // 1024   : b_ih+b_hh, type-major [4][256]
#define OFF_XWB   394752     // 262144 : xw bf16 [B,L,N,128]   (ends 656896)
#define OFF_PHH   656896     // 131072 : packed Whh bf16 frags [slc2][w8][nt4][kt8][lane64][8]
#define OFF_PIH   787968     // 65536  : packed Wih bf16 frags [slc2][w8][nt4][kt4][lane64][8]
#define OFF_HG    853504     // 1048576: h exchange bf16 [128 groups][2 buf][32 rows][256 units] (LINEAR h)
#define OFF_CTR   1902080    // 256    : per-block step counters (int)

typedef __attribute__((ext_vector_type(8))) short short8;
typedef __attribute__((ext_vector_type(4))) float f32x4;

__device__ __forceinline__ float sigf(float x)  { return 1.f / (1.f + __expf(-x)); }
__device__ __forceinline__ float tanhf_(float x){ return 2.f / (1.f + __expf(-2.f * x)) - 1.f; }
__device__ __forceinline__ unsigned short f2b(float f) {
    __hip_bfloat16 h = __float2bfloat16(f);
    return __builtin_bit_cast(unsigned short, h);
}
__device__ __forceinline__ float b2f(unsigned short s) {
    unsigned int u = ((unsigned int)s) << 16;
    return __builtin_bit_cast(float, u);
}
__device__ __forceinline__ f32x4 splat4(float v) { f32x4 r; r[0]=v; r[1]=v; r[2]=v; r[3]=v; return r; }

// ---------- prep: fc_w transpose + MFMA-fragment weight packing + bias + ctr zero ----------
__global__ void k_prep(const float* __restrict__ fc_w, const float* __restrict__ w_ih,
                       const float* __restrict__ w_hh, const float* __restrict__ b_ih,
                       const float* __restrict__ b_hh, float* __restrict__ ws) {
    int i = blockIdx.x * blockDim.x + threadIdx.x;
    unsigned short* phh = (unsigned short*)(ws + OFF_PHH);
    unsigned short* pih = (unsigned short*)(ws + OFF_PIH);
    if (i < 256) ((int*)(ws + OFF_CTR))[i] = 0;
    if (i < 66048) {
        int k = i >> 8, j = i & 255;
        ws[OFF_FCWT + i] = fc_w[j * 258 + k];
    } else if (i < 66048 + 262144) {
        // phh[slc][w][nt][kt][lane][j]
        int p = i - 66048;
        int j = p & 7, lane = (p >> 3) & 63, kt = (p >> 9) & 7, nt = (p >> 12) & 3, w = (p >> 14) & 7, slc = (p >> 17) & 1;
        int n = nt * 256 + slc * 128 + w * 16 + (lane & 15);
        int k = kt * 32 + (lane >> 4) * 8 + j;
        phh[p] = f2b(w_hh[n * 256 + k]);
    } else if (i < 66048 + 262144 + 131072) {
        // pih[slc][w][nt][kt][lane][j]
        int p = i - (66048 + 262144);
        int j = p & 7, lane = (p >> 3) & 63, kt = (p >> 9) & 3, nt = (p >> 11) & 3, w = (p >> 13) & 7, slc = (p >> 16) & 1;
        int n = nt * 256 + slc * 128 + w * 16 + (lane & 15);
        int k = kt * 32 + (lane >> 4) * 8 + j;
        pih[p] = f2b(w_ih[n * 128 + k]);
    } else if (i < 66048 + 262144 + 131072 + 1024) {
        int u = i - (66048 + 262144 + 131072);
        ws[OFF_BIAS + u] = b_ih[u] + b_hh[u];
    }
}

// ---------- fc + layernorm + tanh : one block per (b,n) row ----------
__global__ void k_fc_ln(const float* __restrict__ x, const float* __restrict__ feat,
                        const float* __restrict__ fc_b, const float* __restrict__ ln_g,
                        const float* __restrict__ ln_b, float* __restrict__ ws) {
    __shared__ float inl[260];
    __shared__ float r1[256], r2[256];
    int row = blockIdx.x, tid = threadIdx.x;
    inl[tid] = x[row * H_ + tid];
    if (tid < 2) inl[H_ + tid] = feat[row * 2 + tid];
    __syncthreads();
    const float* fcwT = ws + OFF_FCWT;
    float acc = fc_b[tid];
    #pragma unroll 4
    for (int k = 0; k < 258; ++k) acc += fcwT[k * 256 + tid] * inl[k];
    r1[tid] = acc; r2[tid] = acc * acc;
    __syncthreads();
    for (int o = 128; o > 0; o >>= 1) {
        if (tid < o) { r1[tid] += r1[tid + o]; r2[tid] += r2[tid + o]; }
        __syncthreads();
    }
    float mu  = r1[0] * (1.f / 256.f);
    float var = r2[0] * (1.f / 256.f) - mu * mu;
    float v = (acc - mu) * rsqrtf(var + 1e-5f) * ln_g[tid] + ln_b[tid];
    ws[OFF_H + row * H_ + tid] = tanhf_(v);
}

// ---------- xw[b,l,n,d] = h[b,n,:] @ W[l]  -> bf16 ----------
__global__ void k_xw(const float* __restrict__ Wm, float* __restrict__ ws) {
    __shared__ float hs[32 * 256];
    int bid = blockIdx.x;                    // ((b*4+l)*8 + tile)
    int tile = bid & 7, l = (bid >> 3) & 3, b = bid >> 5;
    int n0 = tile * 32, tid = threadIdx.x;
    const float* hsrc = ws + OFF_H + (b * N_ + n0) * H_;
    for (int i = tid * 4; i < 32 * 256; i += 256 * 4)
        *(float4*)&hs[i] = *(const float4*)&hsrc[i];
    __syncthreads();
    int r0 = (tid >> 5) * 4, c0 = (tid & 31) * 4;
    float acc[4][4] = {};
    const float* wl = Wm + l * H_ * D_;
    for (int k = 0; k < 256; ++k) {
        float4 wv = *(const float4*)&wl[k * D_ + c0];
        #pragma unroll
        for (int r = 0; r < 4; ++r) {
            float hv = hs[(r0 + r) * 256 + k];
            acc[r][0] += hv * wv.x; acc[r][1] += hv * wv.y;
            acc[r][2] += hv * wv.z; acc[r][3] += hv * wv.w;
        }
    }
    unsigned short* xwb = (unsigned short*)(ws + OFF_XWB);
    #pragma unroll
    for (int r = 0; r < 4; ++r) {
        unsigned int lo = (unsigned int)f2b(acc[r][0]) | ((unsigned int)f2b(acc[r][1]) << 16);
        unsigned int hi = (unsigned int)f2b(acc[r][2]) | ((unsigned int)f2b(acc[r][3]) << 16);
        uint2 v; v.x = lo; v.y = hi;
        *(uint2*)&xwb[((b * L_ + l) * N_ + (n0 + r0 + r)) * D_ + c0] = v;
    }
}

// ---------- persistent-weight pairwise LSTM: 256 blocks x 512 thr ----------
// R9 blessed structure. R12: (1) loop fission t<16 / t>=16; (2) h exported directly
// from registers to hg (linear layout: hg[row][cu]) -> barrier E removed (4/step);
// (3) neighbor-index extraction fused into prologue (k_idx kernel removed).
__global__ __launch_bounds__(512, 2)
void k_lstm2(const float* __restrict__ adj, float* __restrict__ out, float* __restrict__ ws) {
    __shared__ __align__(16) unsigned short wih_s[65536];    // 128 KB, Wih slice frags
    __shared__ __align__(16) unsigned short hbuf[32 * 256];  // 16 KB, chunk-swizzled h
    __shared__ int idx_s[32 * 16];                           // 2 KB, neighbor idx
    const int tid = threadIdx.x;
    const int lane = tid & 63, w = tid >> 6;
    const int c15 = lane & 15, lg = lane >> 4;
    const int bid = blockIdx.x;
    const int g = (bid & 7) | ((bid >> 4) << 3);   // 0..127
    const int slc = (bid >> 3) & 1;                // partner = bid^8 (same-XCD heuristic)
    const int partner = bid ^ 8;
    const int gs0 = g * 32;
    const int cu0 = slc * 128 + w * 16 + c15;      // this lane's output unit column

    const unsigned short* pih = (const unsigned short*)(ws + OFF_PIH);
    const float* bias = ws + OFF_BIAS;
    const unsigned short* xwb = (const unsigned short*)(ws + OFF_XWB);
    unsigned short* hg = (unsigned short*)(ws + OFF_HG);     // [128][2][32][256] linear h
    int* ctr = (int*)(ws + OFF_CTR);

    // Wih slice -> LDS (once)
    {
        const uint4* src = (const uint4*)(pih + slc * 65536);
        uint4* dst = (uint4*)wih_s;
        for (int i = tid; i < 8192; i += 512) dst[i] = src[i];
    }
    // zero hbuf
    for (int i = tid; i < 4096; i += 512) ((unsigned int*)hbuf)[i] = 0;
    // fused neighbor-index extraction: wave w handles local seqs w*4 .. w*4+3
    #pragma unroll
    for (int q = 0; q < 4; ++q) {
        int sl = w * 4 + q;
        int gsq = gs0 + sl;
        int bbx = gsq >> 10, nn = (gsq >> 2) & 255, ll = gsq & 3;
        const float* arow = adj + ((size_t)((((bbx << 2) + ll) * 256 + nn))) * 256;
        int base = 0;
        #pragma unroll
        for (int j = 0; j < 4; ++j) {
            bool a = arow[j * 64 + lane] > 0.5f;
            unsigned long long mb = __ballot(a);
            int rank = base + __popcll(mb & ((1ull << lane) - 1ull));
            if (a && rank < DEG_) idx_s[sl * DEG_ + rank] = j * 64 + lane;
            base += __popcll(mb);
        }
    }

    // persistent Whh fragments (loaded once; R9 physical order)
    short8 WH[4][8];
    const short8* ph8 = (const short8*)((const unsigned short*)(ws + OFF_PHH));
    #pragma unroll
    for (int nt = 0; nt < 4; ++nt)
        #pragma unroll
        for (int kt = 0; kt < 8; ++kt)
            WH[nt][kt] = ph8[(((slc * 8 + w) * 32) + nt * 8 + kt) * 64 + lane];

    float bb4[4];
    #pragma unroll
    for (int nt = 0; nt < 4; ++nt) bb4[nt] = bias[nt * 256 + cu0];

    // x gather base per m (lane's A-row = seq gs0 + m*16 + c15)
    int xbb[2];
    #pragma unroll
    for (int m = 0; m < 2; ++m) {
        int gsq = gs0 + m * 16 + c15;
        int bbx = gsq >> 10, ll = gsq & 3;
        xbb[m] = ((bbx << 2) + ll) * 256;
    }

    float cst[2][4];
    #pragma unroll
    for (int m = 0; m < 2; ++m)
        #pragma unroll
        for (int r = 0; r < 4; ++r) cst[m][r] = 0.f;

    // staging map: thread -> (row sr, 8-u16 chunk sch) of the partner 128-unit half
    const int sr = tid >> 4, sch = tid & 15;
    const int slcP = 1 - slc;

    __syncthreads();

    // ================= loop A: t in [0,16) — with x-phase =================
    for (int t = 0; t < DEG_; ++t) {
        const int cur = t & 1, nxt = cur ^ 1;
        if (t > 0) {
            if (tid == 0) {
                while (__hip_atomic_load(ctr + partner, __ATOMIC_RELAXED, __HIP_MEMORY_SCOPE_AGENT) < t)
                    __builtin_amdgcn_s_sleep(1);
            }
            __syncthreads();                       // A: partner h_t published
            {
                const unsigned long long* src = (const unsigned long long*)
                    (hg + ((long)(g * 2 + cur) * 32 + sr) * 256 + slcP * 128 + sch * 8);
                unsigned long long v0 = __hip_atomic_load(src,     __ATOMIC_RELAXED, __HIP_MEMORY_SCOPE_AGENT);
                unsigned long long v1 = __hip_atomic_load(src + 1, __ATOMIC_RELAXED, __HIP_MEMORY_SCOPE_AGENT);
                unsigned short* d = hbuf + sr * 256 + (((slcP * 16 + sch) ^ (sr & 7)) * 8);
                *(unsigned long long*)d = v0;
                *(unsigned long long*)(d + 4) = v1;
            }
            __syncthreads();                       // B: staged
        }

        float hv[2][4];
        #pragma unroll
        for (int m = 0; m < 2; ++m) {
            short8 hA[8];
            #pragma unroll
            for (int kt = 0; kt < 8; ++kt)
                hA[kt] = *(const short8*)&hbuf[(m * 16 + c15) * 256 + (((kt * 4 + lg) ^ (c15 & 7)) * 8)];
            short8 xA[4];
            {
                int nb = idx_s[(m * 16 + c15) * 16 + t];
                const short8* s8 = (const short8*)(xwb + (xbb[m] + nb) * D_);
                #pragma unroll
                for (int kt = 0; kt < 4; ++kt) xA[kt] = s8[kt * 4 + lg];
            }
            f32x4 acc[4];
            #pragma unroll
            for (int nt = 0; nt < 4; ++nt) {
                acc[nt] = splat4(bb4[nt]);
                #pragma unroll
                for (int kt = 0; kt < 8; ++kt)
                    acc[nt] = __builtin_amdgcn_mfma_f32_16x16x32_bf16(hA[kt], WH[nt][kt], acc[nt], 0, 0, 0);
                #pragma unroll
                for (int kt = 0; kt < 4; ++kt) {
                    short8 wf = *(const short8*)&wih_s[(((w * 4 + nt) * 4 + kt) * 64 + lane) * 8];
                    acc[nt] = __builtin_amdgcn_mfma_f32_16x16x32_bf16(xA[kt], wf, acc[nt], 0, 0, 0);
                }
            }
            #pragma unroll
            for (int r = 0; r < 4; ++r) {
                float gi = sigf(acc[0][r]);
                float gf = sigf(acc[1][r]);
                float gg = tanhf_(acc[2][r]);
                float go = sigf(acc[3][r]);
                float cc = gf * cst[m][r] + gi * gg;
                cst[m][r] = cc;
                hv[m][r] = go * tanhf_(cc);
            }
        }
        // export own h_{t+1} directly from regs -> hg[nxt] (linear layout)
        {
            unsigned short* hb = hg + ((long)(g * 2 + nxt) * 32) * 256 + cu0;
            #pragma unroll
            for (int m = 0; m < 2; ++m)
                #pragma unroll
                for (int r = 0; r < 4; ++r)
                    __hip_atomic_store(hb + (m * 16 + lg * 4 + r) * 256, f2b(hv[m][r]),
                                       __ATOMIC_RELAXED, __HIP_MEMORY_SCOPE_AGENT);
        }
        __syncthreads();                           // C: hbuf reads of h_t done
        #pragma unroll
        for (int m = 0; m < 2; ++m)
            #pragma unroll
            for (int r = 0; r < 4; ++r) {
                int row = m * 16 + lg * 4 + r;
                int chunk = (cu0 >> 3) ^ (row & 7);
                hbuf[row * 256 + chunk * 8 + (c15 & 7)] = f2b(hv[m][r]);
            }
        __syncthreads();                           // D: ds writes visible + exports drained
        if (tid == 0)
            __hip_atomic_store(ctr + bid, t + 1, __ATOMIC_RELAXED, __HIP_MEMORY_SCOPE_AGENT);
    }

    // ================= loop B: t in [16,64) — no x-phase =================
    for (int t = DEG_; t < T_; ++t) {
        const int cur = t & 1, nxt = cur ^ 1;
        if (tid == 0) {
            while (__hip_atomic_load(ctr + partner, __ATOMIC_RELAXED, __HIP_MEMORY_SCOPE_AGENT) < t)
                __builtin_amdgcn_s_sleep(1);
        }
        __syncthreads();                           // A
        {
            const unsigned long long* src = (const unsigned long long*)
                (hg + ((long)(g * 2 + cur) * 32 + sr) * 256 + slcP * 128 + sch * 8);
            unsigned long long v0 = __hip_atomic_load(src,     __ATOMIC_RELAXED, __HIP_MEMORY_SCOPE_AGENT);
            unsigned long long v1 = __hip_atomic_load(src + 1, __ATOMIC_RELAXED, __HIP_MEMORY_SCOPE_AGENT);
            unsigned short* d = hbuf + sr * 256 + (((slcP * 16 + sch) ^ (sr & 7)) * 8);
            *(unsigned long long*)d = v0;
            *(unsigned long long*)(d + 4) = v1;
        }
        __syncthreads();                           // B

        float hv[2][4];
        #pragma unroll
        for (int m = 0; m < 2; ++m) {
            short8 hA[8];
            #pragma unroll
            for (int kt = 0; kt < 8; ++kt)
                hA[kt] = *(const short8*)&hbuf[(m * 16 + c15) * 256 + (((kt * 4 + lg) ^ (c15 & 7)) * 8)];
            f32x4 acc[4];
            #pragma unroll
            for (int nt = 0; nt < 4; ++nt) {
                acc[nt] = splat4(bb4[nt]);
                #pragma unroll
                for (int kt = 0; kt < 8; ++kt)
                    acc[nt] = __builtin_amdgcn_mfma_f32_16x16x32_bf16(hA[kt], WH[nt][kt], acc[nt], 0, 0, 0);
            }
            #pragma unroll
            for (int r = 0; r < 4; ++r) {
                float gi = sigf(acc[0][r]);
                float gf = sigf(acc[1][r]);
                float gg = tanhf_(acc[2][r]);
                float go = sigf(acc[3][r]);
                float cc = gf * cst[m][r] + gi * gg;
                cst[m][r] = cc;
                hv[m][r] = go * tanhf_(cc);
            }
        }
        if (t < T_ - 1) {
            unsigned short* hb = hg + ((long)(g * 2 + nxt) * 32) * 256 + cu0;
            #pragma unroll
            for (int m = 0; m < 2; ++m)
                #pragma unroll
                for (int r = 0; r < 4; ++r)
                    __hip_atomic_store(hb + (m * 16 + lg * 4 + r) * 256, f2b(hv[m][r]),
                                       __ATOMIC_RELAXED, __HIP_MEMORY_SCOPE_AGENT);
        }
        __syncthreads();                           // C
        #pragma unroll
        for (int m = 0; m < 2; ++m)
            #pragma unroll
            for (int r = 0; r < 4; ++r) {
                int row = m * 16 + lg * 4 + r;
                int chunk = (cu0 >> 3) ^ (row & 7);
                hbuf[row * 256 + chunk * 8 + (c15 & 7)] = f2b(hv[m][r]);
            }
        __syncthreads();                           // D
        if (tid == 0 && t < T_ - 1)
            __hip_atomic_store(ctr + bid, t + 1, __ATOMIC_RELAXED, __HIP_MEMORY_SCOPE_AGENT);
    }

    // epilogue: out = 2*h_ln + mean_l h_last over this block's 128 units
    const float* hln = ws + OFF_H;
    const int p = tid >> 6, uu = tid & 63;
    const int bn = g * 8 + p;
    #pragma unroll
    for (int j = 0; j < 2; ++j) {
        int cu = slc * 128 + j * 64 + uu;
        float ssum = 0.f;
        #pragma unroll
        for (int l2 = 0; l2 < 4; ++l2) {
            int s = p * 4 + l2;
            ssum += b2f(hbuf[s * 256 + (((cu >> 3) ^ (s & 7)) * 8) + (cu & 7)]);
        }
        int gi = bn * 256 + cu;
        out[gi] = 2.f * hln[gi] + 0.25f * ssum;
    }
}

extern "C" void kernel_launch(void* const* d_in, const int* in_sizes, int n_in,
                              void* d_out, int out_size, void* d_ws, size_t ws_size,
                              hipStream_t stream) {
    const float* x    = (const float*)d_in[0];
    const float* feat = (const float*)d_in[1];
    const float* adj  = (const float*)d_in[2];
    const float* fc_w = (const float*)d_in[3];
    const float* fc_b = (const float*)d_in[4];
    const float* ln_g = (const float*)d_in[5];
    const float* ln_b = (const float*)d_in[6];
    const float* Wm   = (const float*)d_in[7];
    const float* w_ih = (const float*)d_in[8];
    const float* w_hh = (const float*)d_in[9];
    const float* b_ih = (const float*)d_in[10];
    const float* b_hh = (const float*)d_in[11];
    float* ws  = (float*)d_ws;
    float* out = (float*)d_out;

    hipLaunchKernelGGL(k_prep,   dim3(1798), dim3(256), 0, stream, fc_w, w_ih, w_hh, b_ih, b_hh, ws);
    hipLaunchKernelGGL(k_fc_ln,  dim3(1024), dim3(256), 0, stream, x, feat, fc_b, ln_g, ln_b, ws);
    hipLaunchKernelGGL(k_xw,     dim3(128),  dim3(256), 0, stream, Wm, ws);
    hipLaunchKernelGGL(k_lstm2,  dim3(256),  dim3(512), 0, stream, adj, out, ws);
}

// Round 13
// 411.024 us; speedup vs baseline: 1.9020x; 1.9020x over previous
//
#include <hip/hip_runtime.h>
#include <hip/hip_bf16.h>
#include <math.h>

#define B_ 4
#define N_ 256
#define L_ 4
#define H_ 256
#define D_ 128
#define DEG_ 16
#define T_ 64

// ws layout (float units)
#define OFF_H     0          // 262144 : h after fc+LN+tanh (f32) [B*N,256]
#define OFF_FCWT  262144     // 66048  : fc_w transposed [258][256]
#define OFF_BIAS  328192     // 1024   : b_ih+b_hh, type-major [4][256]
#define OFF_XWB   394752     // 262144 : xw bf16 [B,L,N,128]   (ends 656896)
#define OFF_PHH   656896     // 131072 : packed Whh bf16 frags [slc2][w8][nt4][kt8][lane64][8]
#define OFF_PIH   787968     // 65536  : packed Wih bf16 frags [slc2][w8][nt4][kt4][lane64][8]
#define OFF_HG    853504     // 1048576: h exchange bf16 [128 groups][2 buf][32 rows][256 units]
#define OFF_CTR   1902080    // 256    : per-block step counters (int)

typedef __attribute__((ext_vector_type(8))) short short8;
typedef __attribute__((ext_vector_type(4))) float f32x4;

__device__ __forceinline__ float sigf(float x)  { return 1.f / (1.f + __expf(-x)); }
__device__ __forceinline__ float tanhf_(float x){ return 2.f / (1.f + __expf(-2.f * x)) - 1.f; }
__device__ __forceinline__ unsigned short f2b(float f) {
    __hip_bfloat16 h = __float2bfloat16(f);
    return __builtin_bit_cast(unsigned short, h);
}
__device__ __forceinline__ float b2f(unsigned short s) {
    unsigned int u = ((unsigned int)s) << 16;
    return __builtin_bit_cast(float, u);
}
__device__ __forceinline__ f32x4 splat4(float v) { f32x4 r; r[0]=v; r[1]=v; r[2]=v; r[3]=v; return r; }

// ---------- prep: fc_w transpose + MFMA-fragment weight packing + bias + ctr zero ----------
__global__ void k_prep(const float* __restrict__ fc_w, const float* __restrict__ w_ih,
                       const float* __restrict__ w_hh, const float* __restrict__ b_ih,
                       const float* __restrict__ b_hh, float* __restrict__ ws) {
    int i = blockIdx.x * blockDim.x + threadIdx.x;
    unsigned short* phh = (unsigned short*)(ws + OFF_PHH);
    unsigned short* pih = (unsigned short*)(ws + OFF_PIH);
    if (i < 256) ((int*)(ws + OFF_CTR))[i] = 0;
    if (i < 66048) {
        int k = i >> 8, j = i & 255;
        ws[OFF_FCWT + i] = fc_w[j * 258 + k];
    } else if (i < 66048 + 262144) {
        // phh[slc][w][nt][kt][lane][j]
        int p = i - 66048;
        int j = p & 7, lane = (p >> 3) & 63, kt = (p >> 9) & 7, nt = (p >> 12) & 3, w = (p >> 14) & 7, slc = (p >> 17) & 1;
        int n = nt * 256 + slc * 128 + w * 16 + (lane & 15);
        int k = kt * 32 + (lane >> 4) * 8 + j;
        phh[p] = f2b(w_hh[n * 256 + k]);
    } else if (i < 66048 + 262144 + 131072) {
        // pih[slc][w][nt][kt][lane][j]
        int p = i - (66048 + 262144);
        int j = p & 7, lane = (p >> 3) & 63, kt = (p >> 9) & 3, nt = (p >> 11) & 3, w = (p >> 13) & 7, slc = (p >> 16) & 1;
        int n = nt * 256 + slc * 128 + w * 16 + (lane & 15);
        int k = kt * 32 + (lane >> 4) * 8 + j;
        pih[p] = f2b(w_ih[n * 128 + k]);
    } else if (i < 66048 + 262144 + 131072 + 1024) {
        int u = i - (66048 + 262144 + 131072);
        ws[OFF_BIAS + u] = b_ih[u] + b_hh[u];
    }
}

// ---------- fc + layernorm + tanh : one block per (b,n) row ----------
__global__ void k_fc_ln(const float* __restrict__ x, const float* __restrict__ feat,
                        const float* __restrict__ fc_b, const float* __restrict__ ln_g,
                        const float* __restrict__ ln_b, float* __restrict__ ws) {
    __shared__ float inl[260];
    __shared__ float r1[256], r2[256];
    int row = blockIdx.x, tid = threadIdx.x;
    inl[tid] = x[row * H_ + tid];
    if (tid < 2) inl[H_ + tid] = feat[row * 2 + tid];
    __syncthreads();
    const float* fcwT = ws + OFF_FCWT;
    float acc = fc_b[tid];
    #pragma unroll 4
    for (int k = 0; k < 258; ++k) acc += fcwT[k * 256 + tid] * inl[k];
    r1[tid] = acc; r2[tid] = acc * acc;
    __syncthreads();
    for (int o = 128; o > 0; o >>= 1) {
        if (tid < o) { r1[tid] += r1[tid + o]; r2[tid] += r2[tid + o]; }
        __syncthreads();
    }
    float mu  = r1[0] * (1.f / 256.f);
    float var = r2[0] * (1.f / 256.f) - mu * mu;
    float v = (acc - mu) * rsqrtf(var + 1e-5f) * ln_g[tid] + ln_b[tid];
    ws[OFF_H + row * H_ + tid] = tanhf_(v);
}

// ---------- xw[b,l,n,d] = h[b,n,:] @ W[l]  -> bf16 ----------
__global__ void k_xw(const float* __restrict__ Wm, float* __restrict__ ws) {
    __shared__ float hs[32 * 256];
    int bid = blockIdx.x;                    // ((b*4+l)*8 + tile)
    int tile = bid & 7, l = (bid >> 3) & 3, b = bid >> 5;
    int n0 = tile * 32, tid = threadIdx.x;
    const float* hsrc = ws + OFF_H + (b * N_ + n0) * H_;
    for (int i = tid * 4; i < 32 * 256; i += 256 * 4)
        *(float4*)&hs[i] = *(const float4*)&hsrc[i];
    __syncthreads();
    int r0 = (tid >> 5) * 4, c0 = (tid & 31) * 4;
    float acc[4][4] = {};
    const float* wl = Wm + l * H_ * D_;
    for (int k = 0; k < 256; ++k) {
        float4 wv = *(const float4*)&wl[k * D_ + c0];
        #pragma unroll
        for (int r = 0; r < 4; ++r) {
            float hv = hs[(r0 + r) * 256 + k];
            acc[r][0] += hv * wv.x; acc[r][1] += hv * wv.y;
            acc[r][2] += hv * wv.z; acc[r][3] += hv * wv.w;
        }
    }
    unsigned short* xwb = (unsigned short*)(ws + OFF_XWB);
    #pragma unroll
    for (int r = 0; r < 4; ++r) {
        unsigned int lo = (unsigned int)f2b(acc[r][0]) | ((unsigned int)f2b(acc[r][1]) << 16);
        unsigned int hi = (unsigned int)f2b(acc[r][2]) | ((unsigned int)f2b(acc[r][3]) << 16);
        uint2 v; v.x = lo; v.y = hi;
        *(uint2*)&xwb[((b * L_ + l) * N_ + (n0 + r0 + r)) * D_ + c0] = v;
    }
}

// ---------- persistent-weight pairwise LSTM: 256 blocks x 512 thr ----------
// R9 blessed structure, loop body byte-identical. R13 change: neighbor-index
// extraction fused into the prologue (ballot/prefix over adj) -> k_idx kernel
// and its dispatch removed. Everything else untouched.
__global__ __launch_bounds__(512, 2)
void k_lstm2(const float* __restrict__ adj, float* __restrict__ out, float* __restrict__ ws) {
    __shared__ __align__(16) unsigned short wih_s[65536];    // 128 KB, Wih slice frags
    __shared__ __align__(16) unsigned short hbuf[32 * 256];  // 16 KB, chunk-swizzled h
    __shared__ int idx_s[32 * 16];                           // 2 KB, neighbor idx
    const int tid = threadIdx.x;
    const int lane = tid & 63, w = tid >> 6;
    const int c15 = lane & 15, lg = lane >> 4;
    const int bid = blockIdx.x;
    const int g = (bid & 7) | ((bid >> 4) << 3);   // 0..127
    const int slc = (bid >> 3) & 1;                // partner differs in bit 3 -> same XCD
    const int partner = bid ^ 8;
    const int gs0 = g * 32;

    const unsigned short* pih = (const unsigned short*)(ws + OFF_PIH);
    const float* bias = ws + OFF_BIAS;
    const unsigned short* xwb = (const unsigned short*)(ws + OFF_XWB);
    unsigned short* hg = (unsigned short*)(ws + OFF_HG);     // [128][2][32][256]
    int* ctr = (int*)(ws + OFF_CTR);

    // Wih slice -> LDS (once)
    {
        const uint4* src = (const uint4*)(pih + slc * 65536);
        uint4* dst = (uint4*)wih_s;
        for (int i = tid; i < 8192; i += 512) dst[i] = src[i];
    }
    // zero hbuf
    for (int i = tid; i < 4096; i += 512) ((unsigned int*)hbuf)[i] = 0;
    // fused neighbor-index extraction: wave w handles local seqs w*4 .. w*4+3
    #pragma unroll
    for (int q = 0; q < 4; ++q) {
        int sl = w * 4 + q;
        int gsq = gs0 + sl;
        int bbx = gsq >> 10, nn = (gsq >> 2) & 255, ll = gsq & 3;
        const float* arow = adj + ((size_t)((((bbx << 2) + ll) * 256 + nn))) * 256;
        int base = 0;
        #pragma unroll
        for (int j = 0; j < 4; ++j) {
            bool a = arow[j * 64 + lane] > 0.5f;
            unsigned long long mb = __ballot(a);
            int rank = base + __popcll(mb & ((1ull << lane) - 1ull));
            if (a && rank < DEG_) idx_s[sl * DEG_ + rank] = j * 64 + lane;
            base += __popcll(mb);
        }
    }

    // persistent Whh fragments (loaded once)
    short8 WH[4][8];
    const short8* ph8 = (const short8*)((const unsigned short*)(ws + OFF_PHH));
    #pragma unroll
    for (int nt = 0; nt < 4; ++nt)
        #pragma unroll
        for (int kt = 0; kt < 8; ++kt)
            WH[nt][kt] = ph8[(((slc * 8 + w) * 32) + nt * 8 + kt) * 64 + lane];

    float bb4[4];
    #pragma unroll
    for (int nt = 0; nt < 4; ++nt) bb4[nt] = bias[nt * 256 + slc * 128 + w * 16 + c15];

    // x gather base per m (lane's A-row = seq gs0 + m*16 + c15)
    int xbb[2];
    #pragma unroll
    for (int m = 0; m < 2; ++m) {
        int gsq = gs0 + m * 16 + c15;
        int bbx = gsq >> 10, ll = gsq & 3;
        xbb[m] = ((bbx << 2) + ll) * 256;
    }

    float cst[2][4];
    #pragma unroll
    for (int m = 0; m < 2; ++m)
        #pragma unroll
        for (int r = 0; r < 4; ++r) cst[m][r] = 0.f;

    // staging/export map: thread -> (row sr, 8-u16 chunk sch) of a 128-unit half
    const int sr = tid >> 4, sch = tid & 15;
    const int slcP = 1 - slc;

    __syncthreads();

    for (int t = 0; t < T_; ++t) {
        const int cur = t & 1, nxt = cur ^ 1;
        if (t > 0) {
            if (tid == 0) {
                while (__hip_atomic_load(ctr + partner, __ATOMIC_RELAXED, __HIP_MEMORY_SCOPE_AGENT) < t)
                    __builtin_amdgcn_s_sleep(1);
            }
            __syncthreads();
            // stage partner's half of h_t into LDS (swizzled chunks)
            {
                const unsigned long long* src = (const unsigned long long*)
                    (hg + ((long)(g * 2 + cur) * 32 + sr) * 256 + slcP * 128 + sch * 8);
                unsigned long long v0 = __hip_atomic_load(src,     __ATOMIC_RELAXED, __HIP_MEMORY_SCOPE_AGENT);
                unsigned long long v1 = __hip_atomic_load(src + 1, __ATOMIC_RELAXED, __HIP_MEMORY_SCOPE_AGENT);
                unsigned short* d = hbuf + sr * 256 + (((slcP * 16 + sch) ^ (sr & 7)) * 8);
                *(unsigned long long*)d = v0;
                *(unsigned long long*)(d + 4) = v1;
            }
            __syncthreads();
        }

        float hv[2][4];
        #pragma unroll
        for (int m = 0; m < 2; ++m) {
            short8 hA[8];
            #pragma unroll
            for (int kt = 0; kt < 8; ++kt)
                hA[kt] = *(const short8*)&hbuf[(m * 16 + c15) * 256 + (((kt * 4 + lg) ^ (c15 & 7)) * 8)];
            short8 xA[4];
            if (t < DEG_) {
                int nb = idx_s[(m * 16 + c15) * 16 + t];
                const short8* s8 = (const short8*)(xwb + (xbb[m] + nb) * D_);
                #pragma unroll
                for (int kt = 0; kt < 4; ++kt) xA[kt] = s8[kt * 4 + lg];
            }
            f32x4 acc[4];
            #pragma unroll
            for (int nt = 0; nt < 4; ++nt) {
                acc[nt] = splat4(bb4[nt]);
                #pragma unroll
                for (int kt = 0; kt < 8; ++kt)
                    acc[nt] = __builtin_amdgcn_mfma_f32_16x16x32_bf16(hA[kt], WH[nt][kt], acc[nt], 0, 0, 0);
                if (t < DEG_) {
                    #pragma unroll
                    for (int kt = 0; kt < 4; ++kt) {
                        short8 wf = *(const short8*)&wih_s[(((w * 4 + nt) * 4 + kt) * 64 + lane) * 8];
                        acc[nt] = __builtin_amdgcn_mfma_f32_16x16x32_bf16(xA[kt], wf, acc[nt], 0, 0, 0);
                    }
                }
            }
            #pragma unroll
            for (int r = 0; r < 4; ++r) {
                float gi = sigf(acc[0][r]);
                float gf = sigf(acc[1][r]);
                float gg = tanhf_(acc[2][r]);
                float go = sigf(acc[3][r]);
                float cc = gf * cst[m][r] + gi * gg;
                cst[m][r] = cc;
                hv[m][r] = go * tanhf_(cc);
            }
        }
        __syncthreads();   // all hbuf reads of h_t complete
        // write own h_{t+1} into hbuf (own unit columns)
        #pragma unroll
        for (int m = 0; m < 2; ++m)
            #pragma unroll
            for (int r = 0; r < 4; ++r) {
                int row = m * 16 + lg * 4 + r;
                int cu = slc * 128 + w * 16 + c15;
                int chunk = (cu >> 3) ^ (row & 7);
                hbuf[row * 256 + chunk * 8 + (c15 & 7)] = f2b(hv[m][r]);
            }
        __syncthreads();   // own half complete in LDS
        if (t < T_ - 1) {
            // export own half -> hg[nxt]; publish step counter
            const unsigned short* s = hbuf + sr * 256 + (((slc * 16 + sch) ^ (sr & 7)) * 8);
            unsigned long long v0 = *(const unsigned long long*)s;
            unsigned long long v1 = *(const unsigned long long*)(s + 4);
            unsigned long long* d = (unsigned long long*)
                (hg + ((long)(g * 2 + nxt) * 32 + sr) * 256 + slc * 128 + sch * 8);
            __hip_atomic_store(d,     v0, __ATOMIC_RELAXED, __HIP_MEMORY_SCOPE_AGENT);
            __hip_atomic_store(d + 1, v1, __ATOMIC_RELAXED, __HIP_MEMORY_SCOPE_AGENT);
            __syncthreads();   // vmcnt(0) drain block-wide: exports complete
            if (tid == 0)
                __hip_atomic_store(ctr + bid, t + 1, __ATOMIC_RELAXED, __HIP_MEMORY_SCOPE_AGENT);
        }
    }

    // epilogue: out = 2*h_ln + mean_l h_last over this block's 128 units
    const float* hln = ws + OFF_H;
    const int p = tid >> 6, uu = tid & 63;
    const int bn = g * 8 + p;
    #pragma unroll
    for (int j = 0; j < 2; ++j) {
        int cu = slc * 128 + j * 64 + uu;
        float ssum = 0.f;
        #pragma unroll
        for (int l2 = 0; l2 < 4; ++l2) {
            int s = p * 4 + l2;
            ssum += b2f(hbuf[s * 256 + (((cu >> 3) ^ (s & 7)) * 8) + (cu & 7)]);
        }
        int gi = bn * 256 + cu;
        out[gi] = 2.f * hln[gi] + 0.25f * ssum;
    }
}

extern "C" void kernel_launch(void* const* d_in, const int* in_sizes, int n_in,
                              void* d_out, int out_size, void* d_ws, size_t ws_size,
                              hipStream_t stream) {
    const float* x    = (const float*)d_in[0];
    const float* feat = (const float*)d_in[1];
    const float* adj  = (const float*)d_in[2];
    const float* fc_w = (const float*)d_in[3];
    const float* fc_b = (const float*)d_in[4];
    const float* ln_g = (const float*)d_in[5];
    const float* ln_b = (const float*)d_in[6];
    const float* Wm   = (const float*)d_in[7];
    const float* w_ih = (const float*)d_in[8];
    const float* w_hh = (const float*)d_in[9];
    const float* b_ih = (const float*)d_in[10];
    const float* b_hh = (const float*)d_in[11];
    float* ws  = (float*)d_ws;
    float* out = (float*)d_out;

    hipLaunchKernelGGL(k_prep,   dim3(1798), dim3(256), 0, stream, fc_w, w_ih, w_hh, b_ih, b_hh, ws);
    hipLaunchKernelGGL(k_fc_ln,  dim3(1024), dim3(256), 0, stream, x, feat, fc_b, ln_g, ln_b, ws);
    hipLaunchKernelGGL(k_xw,     dim3(128),  dim3(256), 0, stream, Wm, ws);
    hipLaunchKernelGGL(k_lstm2,  dim3(256),  dim3(512), 0, stream, adj, out, ws);
}

// Round 14
// 409.854 us; speedup vs baseline: 1.9074x; 1.0029x over previous
//
#include <hip/hip_runtime.h>
#include <hip/hip_bf16.h>
#include <math.h>

#define B_ 4
#define N_ 256
#define L_ 4
#define H_ 256
#define D_ 128
#define DEG_ 16
#define T_ 64

// ws layout (float units)
#define OFF_H     0          // 262144 : h after fc+LN+tanh (f32) [B*N,256]
#define OFF_FCWT  262144     // 66048  : fc_w transposed [258][256]
#define OFF_BIAS  328192     // 1024   : b_ih+b_hh, type-major [4][256]
#define OFF_XWB   394752     // 262144 : xw bf16 [B,L,N,128]   (ends 656896)
#define OFF_PHH   656896     // 131072 : packed Whh bf16 frags [slc2][w8][nt4][kt8][lane64][8]
#define OFF_PIH   787968     // 65536  : packed Wih bf16 frags [slc2][w8][nt4][kt4][lane64][8]
#define OFF_HG    853504     // 1048576: h exchange bf16 [128 groups][2 buf][32 rows][256 units]
#define OFF_CTR   1902080    // 256    : per-block step counters (int)

typedef __attribute__((ext_vector_type(8))) short short8;
typedef __attribute__((ext_vector_type(4))) float f32x4;

__device__ __forceinline__ float sigf(float x)  { return 1.f / (1.f + __expf(-x)); }
__device__ __forceinline__ float tanhf_(float x){ return 2.f / (1.f + __expf(-2.f * x)) - 1.f; }
__device__ __forceinline__ unsigned short f2b(float f) {
    __hip_bfloat16 h = __float2bfloat16(f);
    return __builtin_bit_cast(unsigned short, h);
}
__device__ __forceinline__ float b2f(unsigned short s) {
    unsigned int u = ((unsigned int)s) << 16;
    return __builtin_bit_cast(float, u);
}
__device__ __forceinline__ f32x4 splat4(float v) { f32x4 r; r[0]=v; r[1]=v; r[2]=v; r[3]=v; return r; }

// ---------- prep: fc_w transpose + MFMA-fragment weight packing + bias + ctr zero ----------
__global__ void k_prep(const float* __restrict__ fc_w, const float* __restrict__ w_ih,
                       const float* __restrict__ w_hh, const float* __restrict__ b_ih,
                       const float* __restrict__ b_hh, float* __restrict__ ws) {
    int i = blockIdx.x * blockDim.x + threadIdx.x;
    unsigned short* phh = (unsigned short*)(ws + OFF_PHH);
    unsigned short* pih = (unsigned short*)(ws + OFF_PIH);
    if (i < 256) ((int*)(ws + OFF_CTR))[i] = 0;
    if (i < 66048) {
        int k = i >> 8, j = i & 255;
        ws[OFF_FCWT + i] = fc_w[j * 258 + k];
    } else if (i < 66048 + 262144) {
        // phh[slc][w][nt][kt][lane][j]
        int p = i - 66048;
        int j = p & 7, lane = (p >> 3) & 63, kt = (p >> 9) & 7, nt = (p >> 12) & 3, w = (p >> 14) & 7, slc = (p >> 17) & 1;
        int n = nt * 256 + slc * 128 + w * 16 + (lane & 15);
        int k = kt * 32 + (lane >> 4) * 8 + j;
        phh[p] = f2b(w_hh[n * 256 + k]);
    } else if (i < 66048 + 262144 + 131072) {
        // pih[slc][w][nt][kt][lane][j]
        int p = i - (66048 + 262144);
        int j = p & 7, lane = (p >> 3) & 63, kt = (p >> 9) & 3, nt = (p >> 11) & 3, w = (p >> 13) & 7, slc = (p >> 16) & 1;
        int n = nt * 256 + slc * 128 + w * 16 + (lane & 15);
        int k = kt * 32 + (lane >> 4) * 8 + j;
        pih[p] = f2b(w_ih[n * 128 + k]);
    } else if (i < 66048 + 262144 + 131072 + 1024) {
        int u = i - (66048 + 262144 + 131072);
        ws[OFF_BIAS + u] = b_ih[u] + b_hh[u];
    }
}

// ---------- fc + layernorm + tanh : one block per (b,n) row ----------
__global__ void k_fc_ln(const float* __restrict__ x, const float* __restrict__ feat,
                        const float* __restrict__ fc_b, const float* __restrict__ ln_g,
                        const float* __restrict__ ln_b, float* __restrict__ ws) {
    __shared__ float inl[260];
    __shared__ float r1[256], r2[256];
    int row = blockIdx.x, tid = threadIdx.x;
    inl[tid] = x[row * H_ + tid];
    if (tid < 2) inl[H_ + tid] = feat[row * 2 + tid];
    __syncthreads();
    const float* fcwT = ws + OFF_FCWT;
    float acc = fc_b[tid];
    #pragma unroll 4
    for (int k = 0; k < 258; ++k) acc += fcwT[k * 256 + tid] * inl[k];
    r1[tid] = acc; r2[tid] = acc * acc;
    __syncthreads();
    for (int o = 128; o > 0; o >>= 1) {
        if (tid < o) { r1[tid] += r1[tid + o]; r2[tid] += r2[tid + o]; }
        __syncthreads();
    }
    float mu  = r1[0] * (1.f / 256.f);
    float var = r2[0] * (1.f / 256.f) - mu * mu;
    float v = (acc - mu) * rsqrtf(var + 1e-5f) * ln_g[tid] + ln_b[tid];
    ws[OFF_H + row * H_ + tid] = tanhf_(v);
}

// ---------- xw[b,l,n,d] = h[b,n,:] @ W[l]  -> bf16 ----------
__global__ void k_xw(const float* __restrict__ Wm, float* __restrict__ ws) {
    __shared__ float hs[32 * 256];
    int bid = blockIdx.x;                    // ((b*4+l)*8 + tile)
    int tile = bid & 7, l = (bid >> 3) & 3, b = bid >> 5;
    int n0 = tile * 32, tid = threadIdx.x;
    const float* hsrc = ws + OFF_H + (b * N_ + n0) * H_;
    for (int i = tid * 4; i < 32 * 256; i += 256 * 4)
        *(float4*)&hs[i] = *(const float4*)&hsrc[i];
    __syncthreads();
    int r0 = (tid >> 5) * 4, c0 = (tid & 31) * 4;
    float acc[4][4] = {};
    const float* wl = Wm + l * H_ * D_;
    for (int k = 0; k < 256; ++k) {
        float4 wv = *(const float4*)&wl[k * D_ + c0];
        #pragma unroll
        for (int r = 0; r < 4; ++r) {
            float hv = hs[(r0 + r) * 256 + k];
            acc[r][0] += hv * wv.x; acc[r][1] += hv * wv.y;
            acc[r][2] += hv * wv.z; acc[r][3] += hv * wv.w;
        }
    }
    unsigned short* xwb = (unsigned short*)(ws + OFF_XWB);
    #pragma unroll
    for (int r = 0; r < 4; ++r) {
        unsigned int lo = (unsigned int)f2b(acc[r][0]) | ((unsigned int)f2b(acc[r][1]) << 16);
        unsigned int hi = (unsigned int)f2b(acc[r][2]) | ((unsigned int)f2b(acc[r][3]) << 16);
        uint2 v; v.x = lo; v.y = hi;
        *(uint2*)&xwb[((b * L_ + l) * N_ + (n0 + r0 + r)) * D_ + c0] = v;
    }
}

// ---------- persistent-weight pairwise LSTM: 256 blocks x 512 thr ----------
// R13 structure, loop body byte-identical from barrier B onward. R14 change:
// barrier A removed — ALL threads spin on the partner counter (each thread's
// hg loads are ordered behind its own spin branch; barrier B still orders
// stage-writes vs reads). Publisher side unchanged.
__global__ __launch_bounds__(512, 2)
void k_lstm2(const float* __restrict__ adj, float* __restrict__ out, float* __restrict__ ws) {
    __shared__ __align__(16) unsigned short wih_s[65536];    // 128 KB, Wih slice frags
    __shared__ __align__(16) unsigned short hbuf[32 * 256];  // 16 KB, chunk-swizzled h
    __shared__ int idx_s[32 * 16];                           // 2 KB, neighbor idx
    const int tid = threadIdx.x;
    const int lane = tid & 63, w = tid >> 6;
    const int c15 = lane & 15, lg = lane >> 4;
    const int bid = blockIdx.x;
    const int g = (bid & 7) | ((bid >> 4) << 3);   // 0..127
    const int slc = (bid >> 3) & 1;                // partner differs in bit 3 -> same XCD
    const int partner = bid ^ 8;
    const int gs0 = g * 32;

    const unsigned short* pih = (const unsigned short*)(ws + OFF_PIH);
    const float* bias = ws + OFF_BIAS;
    const unsigned short* xwb = (const unsigned short*)(ws + OFF_XWB);
    unsigned short* hg = (unsigned short*)(ws + OFF_HG);     // [128][2][32][256]
    int* ctr = (int*)(ws + OFF_CTR);

    // Wih slice -> LDS (once)
    {
        const uint4* src = (const uint4*)(pih + slc * 65536);
        uint4* dst = (uint4*)wih_s;
        for (int i = tid; i < 8192; i += 512) dst[i] = src[i];
    }
    // zero hbuf
    for (int i = tid; i < 4096; i += 512) ((unsigned int*)hbuf)[i] = 0;
    // fused neighbor-index extraction: wave w handles local seqs w*4 .. w*4+3
    #pragma unroll
    for (int q = 0; q < 4; ++q) {
        int sl = w * 4 + q;
        int gsq = gs0 + sl;
        int bbx = gsq >> 10, nn = (gsq >> 2) & 255, ll = gsq & 3;
        const float* arow = adj + ((size_t)((((bbx << 2) + ll) * 256 + nn))) * 256;
        int base = 0;
        #pragma unroll
        for (int j = 0; j < 4; ++j) {
            bool a = arow[j * 64 + lane] > 0.5f;
            unsigned long long mb = __ballot(a);
            int rank = base + __popcll(mb & ((1ull << lane) - 1ull));
            if (a && rank < DEG_) idx_s[sl * DEG_ + rank] = j * 64 + lane;
            base += __popcll(mb);
        }
    }

    // persistent Whh fragments (loaded once)
    short8 WH[4][8];
    const short8* ph8 = (const short8*)((const unsigned short*)(ws + OFF_PHH));
    #pragma unroll
    for (int nt = 0; nt < 4; ++nt)
        #pragma unroll
        for (int kt = 0; kt < 8; ++kt)
            WH[nt][kt] = ph8[(((slc * 8 + w) * 32) + nt * 8 + kt) * 64 + lane];

    float bb4[4];
    #pragma unroll
    for (int nt = 0; nt < 4; ++nt) bb4[nt] = bias[nt * 256 + slc * 128 + w * 16 + c15];

    // x gather base per m (lane's A-row = seq gs0 + m*16 + c15)
    int xbb[2];
    #pragma unroll
    for (int m = 0; m < 2; ++m) {
        int gsq = gs0 + m * 16 + c15;
        int bbx = gsq >> 10, ll = gsq & 3;
        xbb[m] = ((bbx << 2) + ll) * 256;
    }

    float cst[2][4];
    #pragma unroll
    for (int m = 0; m < 2; ++m)
        #pragma unroll
        for (int r = 0; r < 4; ++r) cst[m][r] = 0.f;

    // staging/export map: thread -> (row sr, 8-u16 chunk sch) of a 128-unit half
    const int sr = tid >> 4, sch = tid & 15;
    const int slcP = 1 - slc;

    __syncthreads();

    for (int t = 0; t < T_; ++t) {
        const int cur = t & 1, nxt = cur ^ 1;
        if (t > 0) {
            // all-threads spin: each thread's stage loads are ordered behind its
            // own spin branch (ctr value feeds the branch); no block barrier needed
            while (__hip_atomic_load(ctr + partner, __ATOMIC_RELAXED, __HIP_MEMORY_SCOPE_AGENT) < t)
                __builtin_amdgcn_s_sleep(1);
            // stage partner's half of h_t into LDS (swizzled chunks)
            {
                const unsigned long long* src = (const unsigned long long*)
                    (hg + ((long)(g * 2 + cur) * 32 + sr) * 256 + slcP * 128 + sch * 8);
                unsigned long long v0 = __hip_atomic_load(src,     __ATOMIC_RELAXED, __HIP_MEMORY_SCOPE_AGENT);
                unsigned long long v1 = __hip_atomic_load(src + 1, __ATOMIC_RELAXED, __HIP_MEMORY_SCOPE_AGENT);
                unsigned short* d = hbuf + sr * 256 + (((slcP * 16 + sch) ^ (sr & 7)) * 8);
                *(unsigned long long*)d = v0;
                *(unsigned long long*)(d + 4) = v1;
            }
            __syncthreads();   // B: staged data visible block-wide
        }

        float hv[2][4];
        #pragma unroll
        for (int m = 0; m < 2; ++m) {
            short8 hA[8];
            #pragma unroll
            for (int kt = 0; kt < 8; ++kt)
                hA[kt] = *(const short8*)&hbuf[(m * 16 + c15) * 256 + (((kt * 4 + lg) ^ (c15 & 7)) * 8)];
            short8 xA[4];
            if (t < DEG_) {
                int nb = idx_s[(m * 16 + c15) * 16 + t];
                const short8* s8 = (const short8*)(xwb + (xbb[m] + nb) * D_);
                #pragma unroll
                for (int kt = 0; kt < 4; ++kt) xA[kt] = s8[kt * 4 + lg];
            }
            f32x4 acc[4];
            #pragma unroll
            for (int nt = 0; nt < 4; ++nt) {
                acc[nt] = splat4(bb4[nt]);
                #pragma unroll
                for (int kt = 0; kt < 8; ++kt)
                    acc[nt] = __builtin_amdgcn_mfma_f32_16x16x32_bf16(hA[kt], WH[nt][kt], acc[nt], 0, 0, 0);
                if (t < DEG_) {
                    #pragma unroll
                    for (int kt = 0; kt < 4; ++kt) {
                        short8 wf = *(const short8*)&wih_s[(((w * 4 + nt) * 4 + kt) * 64 + lane) * 8];
                        acc[nt] = __builtin_amdgcn_mfma_f32_16x16x32_bf16(xA[kt], wf, acc[nt], 0, 0, 0);
                    }
                }
            }
            #pragma unroll
            for (int r = 0; r < 4; ++r) {
                float gi = sigf(acc[0][r]);
                float gf = sigf(acc[1][r]);
                float gg = tanhf_(acc[2][r]);
                float go = sigf(acc[3][r]);
                float cc = gf * cst[m][r] + gi * gg;
                cst[m][r] = cc;
                hv[m][r] = go * tanhf_(cc);
            }
        }
        __syncthreads();   // C: all hbuf reads of h_t complete
        // write own h_{t+1} into hbuf (own unit columns)
        #pragma unroll
        for (int m = 0; m < 2; ++m)
            #pragma unroll
            for (int r = 0; r < 4; ++r) {
                int row = m * 16 + lg * 4 + r;
                int cu = slc * 128 + w * 16 + c15;
                int chunk = (cu >> 3) ^ (row & 7);
                hbuf[row * 256 + chunk * 8 + (c15 & 7)] = f2b(hv[m][r]);
            }
        __syncthreads();   // D: own half complete in LDS
        if (t < T_ - 1) {
            // export own half -> hg[nxt]; publish step counter
            const unsigned short* s = hbuf + sr * 256 + (((slc * 16 + sch) ^ (sr & 7)) * 8);
            unsigned long long v0 = *(const unsigned long long*)s;
            unsigned long long v1 = *(const unsigned long long*)(s + 4);
            unsigned long long* d = (unsigned long long*)
                (hg + ((long)(g * 2 + nxt) * 32 + sr) * 256 + slc * 128 + sch * 8);
            __hip_atomic_store(d,     v0, __ATOMIC_RELAXED, __HIP_MEMORY_SCOPE_AGENT);
            __hip_atomic_store(d + 1, v1, __ATOMIC_RELAXED, __HIP_MEMORY_SCOPE_AGENT);
            __syncthreads();   // E: vmcnt(0) drain block-wide: exports complete
            if (tid == 0)
                __hip_atomic_store(ctr + bid, t + 1, __ATOMIC_RELAXED, __HIP_MEMORY_SCOPE_AGENT);
        }
    }

    // epilogue: out = 2*h_ln + mean_l h_last over this block's 128 units
    const float* hln = ws + OFF_H;
    const int p = tid >> 6, uu = tid & 63;
    const int bn = g * 8 + p;
    #pragma unroll
    for (int j = 0; j < 2; ++j) {
        int cu = slc * 128 + j * 64 + uu;
        float ssum = 0.f;
        #pragma unroll
        for (int l2 = 0; l2 < 4; ++l2) {
            int s = p * 4 + l2;
            ssum += b2f(hbuf[s * 256 + (((cu >> 3) ^ (s & 7)) * 8) + (cu & 7)]);
        }
        int gi = bn * 256 + cu;
        out[gi] = 2.f * hln[gi] + 0.25f * ssum;
    }
}

extern "C" void kernel_launch(void* const* d_in, const int* in_sizes, int n_in,
                              void* d_out, int out_size, void* d_ws, size_t ws_size,
                              hipStream_t stream) {
    const float* x    = (const float*)d_in[0];
    const float* feat = (const float*)d_in[1];
    const float* adj  = (const float*)d_in[2];
    const float* fc_w = (const float*)d_in[3];
    const float* fc_b = (const float*)d_in[4];
    const float* ln_g = (const float*)d_in[5];
    const float* ln_b = (const float*)d_in[6];
    const float* Wm   = (const float*)d_in[7];
    const float* w_ih = (const float*)d_in[8];
    const float* w_hh = (const float*)d_in[9];
    const float* b_ih = (const float*)d_in[10];
    const float* b_hh = (const float*)d_in[11];
    float* ws  = (float*)d_ws;
    float* out = (float*)d_out;

    hipLaunchKernelGGL(k_prep,   dim3(1798), dim3(256), 0, stream, fc_w, w_ih, w_hh, b_ih, b_hh, ws);
    hipLaunchKernelGGL(k_fc_ln,  dim3(1024), dim3(256), 0, stream, x, feat, fc_b, ln_g, ln_b, ws);
    hipLaunchKernelGGL(k_xw,     dim3(128),  dim3(256), 0, stream, Wm, ws);
    hipLaunchKernelGGL(k_lstm2,  dim3(256),  dim3(512), 0, stream, adj, out, ws);
}